// Round 8
// baseline (123.746 us; speedup 1.0000x reference)
//
#include <hip/hip_runtime.h>

#define D 256
#define W8 2048

// workspace float offsets
#define TCARD_OFF   0                 // 53*256  (pre-scaled by 1/7)
#define THERO_OFF   13568             // 9*256
#define TACT_OFF    15872             // 9*256
#define TNUMP_OFF   18176             // 10*256
#define WSC_OFF     20736             // 2*256 (transposed [k][d])  -- rows 0..1
#define WBET_OFF    21248             // 9*256                      -- rows 2..10
#define WACT_OFF    23552             // 8*256                      -- rows 11..18
#define WBL_OFF     25600             // 2*256                      -- rows 19..20
#define BPART_OFF   26112             // 4*256 bias partials
// NOTE: WSC..WBL are 21 contiguous rows — embed_kernel copies them as one slab.

typedef float nf4 __attribute__((ext_vector_type(4)));               // native vec (nontemporal store)
typedef float f4a4 __attribute__((ext_vector_type(4), aligned(4)));  // under-aligned vec loads

__device__ __forceinline__ void f4acc(float4& a, const float4 b) {
    a.x += b.x; a.y += b.y; a.z += b.z; a.w += b.w;
}
__device__ __forceinline__ void f4fma(float4& a, float v, const float4 b) {
    a.x += v * b.x; a.y += v * b.y; a.z += v * b.z; a.w += v * b.w;
}

// -------- precompute: fold combine_W into tables & section weights --------

template <int NK>
__device__ void fuse_section(const float* __restrict__ combine_W, int wblk,
                             const float* __restrict__ sw,   // LDS [NK][D]
                             const float* __restrict__ sb,   // LDS [D]
                             float* __restrict__ dstT,       // ws [NK][D]
                             float* __restrict__ bpart,      // ws [D]
                             int d)
{
    float acc[NK];
#pragma unroll
    for (int k = 0; k < NK; ++k) acc[k] = 0.f;
    float accb = 0.f;
    const float* wrow = combine_W + (size_t)d * W8 + wblk * D;
    for (int dd = 0; dd < D; dd += 4) {
        float4 w = *(const float4*)(wrow + dd);
        accb += w.x * sb[dd] + w.y * sb[dd + 1] + w.z * sb[dd + 2] + w.w * sb[dd + 3];
#pragma unroll
        for (int k = 0; k < NK; ++k) {
            const float* s = sw + k * D + dd;
            acc[k] += w.x * s[0] + w.y * s[1] + w.z * s[2] + w.w * s[3];
        }
    }
#pragma unroll
    for (int k = 0; k < NK; ++k) dstT[k * D + d] = acc[k];
    bpart[d] = accb;
}

__global__ __launch_bounds__(256) void fuse_kernel(
    const float* __restrict__ combine_W,
    const float* __restrict__ card_t, const float* __restrict__ hero_t,
    const float* __restrict__ act_t,  const float* __restrict__ nump_t,
    const float* __restrict__ scalar_W, const float* __restrict__ scalar_b,
    const float* __restrict__ blind_W,  const float* __restrict__ blind_b,
    const float* __restrict__ bet_W,    const float* __restrict__ bet_b,
    const float* __restrict__ action_W, const float* __restrict__ action_b,
    float* __restrict__ ws)
{
    __shared__ float sh[10 * D];  // 10 KB
    const int blk = blockIdx.x;
    const int d = threadIdx.x;

    if (blk < 81) {
        // fused embedding-table rows: T[r,d] = sum_k Wblk[d,k] * table[r,k]
        const float* src; int wblk; float* dst; float scale;
        if (blk < 53)      { src = card_t + blk * D;        wblk = 0; dst = ws + TCARD_OFF + blk * D; scale = 1.0f / 7.0f; }
        else if (blk < 62) { src = hero_t + (blk - 53) * D; wblk = 1; dst = ws + THERO_OFF + (blk - 53) * D; scale = 1.0f; }
        else if (blk < 71) { src = act_t  + (blk - 62) * D; wblk = 2; dst = ws + TACT_OFF  + (blk - 62) * D; scale = 1.0f; }
        else               { src = nump_t + (blk - 71) * D; wblk = 6; dst = ws + TNUMP_OFF + (blk - 71) * D; scale = 1.0f; }
        sh[d] = src[d];
        __syncthreads();
        const float* wrow = combine_W + (size_t)d * W8 + wblk * D;
        float a0 = 0.f, a1 = 0.f, a2 = 0.f, a3 = 0.f;
#pragma unroll 8
        for (int k = 0; k < D; k += 4) {
            float4 w = *(const float4*)(wrow + k);
            a0 += w.x * sh[k];     a1 += w.y * sh[k + 1];
            a2 += w.z * sh[k + 2]; a3 += w.w * sh[k + 3];
        }
        dst[d] = ((a0 + a1) + (a2 + a3)) * scale;
    } else {
        // fused linear-section weights (stored transposed [k][d]) + bias partials
        const int sec = blk - 81;
        const float* secW; const float* secB; int nk, wblk; float* dstT;
        switch (sec) {
            case 0:  secW = scalar_W; secB = scalar_b; nk = 2; wblk = 3; dstT = ws + WSC_OFF;  break;
            case 1:  secW = bet_W;    secB = bet_b;    nk = 9; wblk = 4; dstT = ws + WBET_OFF; break;
            case 2:  secW = action_W; secB = action_b; nk = 8; wblk = 5; dstT = ws + WACT_OFF; break;
            default: secW = blind_W;  secB = blind_b;  nk = 2; wblk = 7; dstT = ws + WBL_OFF;  break;
        }
        for (int k = 0; k < nk; ++k) sh[k * D + d] = secW[d * nk + k];  // transpose into LDS
        sh[9 * D + d] = secB[d];
        __syncthreads();
        float* bpart = ws + BPART_OFF + sec * D;
        if (nk == 2)      fuse_section<2>(combine_W, wblk, sh, sh + 9 * D, dstT, bpart, d);
        else if (nk == 8) fuse_section<8>(combine_W, wblk, sh, sh + 9 * D, dstT, bpart, d);
        else              fuse_section<9>(combine_W, wblk, sh, sh + 9 * D, dstT, bpart, d);
    }
}

// -------- main: R5 structure (TPW=1, weights in 22.5 KB LDS) + occupancy ----
// Cross-round evidence: perf tracks occupancy (R1 61%->48us, R5 ~40%->~29us,
// R7 17%->44us, R3 11%->94us). TPW=1 is the proven best wave shape. Here we
// pin VGPR <= 73 via __launch_bounds__(256,7) (7 waves/SIMD) and launch 2048
// blocks (22.5 KB LDS -> 7 resident blocks/CU = 28 waves/CU).

#define EMB_BLOCKS 2048
#define EMB_THREADS 256
#define EMB_WAVES (EMB_THREADS / 64)
#define WROWS 22   // 21 weight rows + 1 fused-bias row

__global__ __launch_bounds__(EMB_THREADS, 7) void embed_kernel(
    const int* __restrict__ cards,  const int* __restrict__ hero,
    const int* __restrict__ acting, const int* __restrict__ nump,
    const float* __restrict__ scalars, const float* __restrict__ blinds,
    const float* __restrict__ bets,    const float* __restrict__ action,
    const float* __restrict__ mask,    const float* __restrict__ combine_b,
    const float* __restrict__ ws, float* __restrict__ out, int ntok)
{
    __shared__ __align__(16) float wlds[WROWS * D];  // 22528 B

    const int tid = threadIdx.x;

    // rows 0..20: one contiguous slab ws[WSC_OFF .. WSC_OFF+21*256)
    {
        const float4* src = (const float4*)(ws + WSC_OFF);
        float4* dst = (float4*)wlds;
        for (int i = tid; i < 21 * (D / 4); i += EMB_THREADS) dst[i] = src[i];
        // row 21: fused bias = combine_b + 4 section-bias partials
        wlds[21 * D + tid] = combine_b[tid]
            + ws[BPART_OFF + 0 * D + tid] + ws[BPART_OFF + 1 * D + tid]
            + ws[BPART_OFF + 2 * D + tid] + ws[BPART_OFF + 3 * D + tid];
    }
    __syncthreads();

    const int lane = tid & 63;
    const int wave = tid >> 6;
    const int d0 = lane * 4;

    const int gw = blockIdx.x * EMB_WAVES + wave;
    const int nw = EMB_BLOCKS * EMB_WAVES;

    for (int tok = gw; tok < ntok; tok += nw) {
        // acc0: gathers (cards + embeds) + bias; acc1: sections — two chains
        float4 acc0 = *(const float4*)(wlds + 21 * D + d0);  // bias
        float4 acc1 = {0.f, 0.f, 0.f, 0.f};

        // contiguous, mergeable feature loads (vectorized)
        const f4a4 bt0 = *(const f4a4*)(bets + (size_t)tok * 9);
        const f4a4 bt1 = *(const f4a4*)(bets + (size_t)tok * 9 + 4);
        const float bt8 = bets[(size_t)tok * 9 + 8];
        const float4 fa0 = *(const float4*)(action + (size_t)tok * 8);
        const float4 fa1 = *(const float4*)(action + (size_t)tok * 8 + 4);
        const float2 fs = *(const float2*)(scalars + (size_t)tok * 2);
        const float2 fl = *(const float2*)(blinds + (size_t)tok * 2);
        const float m = mask[tok];

        // gathers from L2-resident ws
        const int* cp = cards + (size_t)tok * 7;
#pragma unroll
        for (int j = 0; j < 7; ++j)
            f4acc(acc0, *(const float4*)(ws + TCARD_OFF + cp[j] * D + d0));
        f4acc(acc0, *(const float4*)(ws + THERO_OFF + hero[tok]   * D + d0));
        f4acc(acc0, *(const float4*)(ws + TACT_OFF  + acting[tok] * D + d0));
        f4acc(acc0, *(const float4*)(ws + TNUMP_OFF + nump[tok]   * D + d0));

        // 21-row LDS weight sweep
        f4fma(acc1, fs.x,  *(const float4*)(wlds + 0  * D + d0));
        f4fma(acc1, fs.y,  *(const float4*)(wlds + 1  * D + d0));
        f4fma(acc1, bt0.x, *(const float4*)(wlds + 2  * D + d0));
        f4fma(acc1, bt0.y, *(const float4*)(wlds + 3  * D + d0));
        f4fma(acc1, bt0.z, *(const float4*)(wlds + 4  * D + d0));
        f4fma(acc1, bt0.w, *(const float4*)(wlds + 5  * D + d0));
        f4fma(acc1, bt1.x, *(const float4*)(wlds + 6  * D + d0));
        f4fma(acc1, bt1.y, *(const float4*)(wlds + 7  * D + d0));
        f4fma(acc1, bt1.z, *(const float4*)(wlds + 8  * D + d0));
        f4fma(acc1, bt1.w, *(const float4*)(wlds + 9  * D + d0));
        f4fma(acc1, bt8,   *(const float4*)(wlds + 10 * D + d0));
        f4fma(acc1, fa0.x, *(const float4*)(wlds + 11 * D + d0));
        f4fma(acc1, fa0.y, *(const float4*)(wlds + 12 * D + d0));
        f4fma(acc1, fa0.z, *(const float4*)(wlds + 13 * D + d0));
        f4fma(acc1, fa0.w, *(const float4*)(wlds + 14 * D + d0));
        f4fma(acc1, fa1.x, *(const float4*)(wlds + 15 * D + d0));
        f4fma(acc1, fa1.y, *(const float4*)(wlds + 16 * D + d0));
        f4fma(acc1, fa1.z, *(const float4*)(wlds + 17 * D + d0));
        f4fma(acc1, fa1.w, *(const float4*)(wlds + 18 * D + d0));
        f4fma(acc1, fl.x,  *(const float4*)(wlds + 19 * D + d0));
        f4fma(acc1, fl.y,  *(const float4*)(wlds + 20 * D + d0));

        nf4 o;
        o.x = (acc0.x + acc1.x) * m; o.y = (acc0.y + acc1.y) * m;
        o.z = (acc0.z + acc1.z) * m; o.w = (acc0.w + acc1.w) * m;
        __builtin_nontemporal_store(o, (nf4*)(out + (size_t)tok * D + d0));
    }
}

extern "C" void kernel_launch(void* const* d_in, const int* in_sizes, int n_in,
                              void* d_out, int out_size, void* d_ws, size_t ws_size,
                              hipStream_t stream) {
    const int*   cards    = (const int*)d_in[0];
    const int*   hero     = (const int*)d_in[1];
    const int*   acting   = (const int*)d_in[2];
    const int*   nump     = (const int*)d_in[3];
    const float* scalars  = (const float*)d_in[4];
    const float* blinds   = (const float*)d_in[5];
    const float* bets     = (const float*)d_in[6];
    const float* action   = (const float*)d_in[7];
    const float* mask     = (const float*)d_in[8];
    const float* card_t   = (const float*)d_in[9];
    const float* hero_t   = (const float*)d_in[10];
    const float* act_t    = (const float*)d_in[11];
    const float* nump_t   = (const float*)d_in[12];
    const float* scalar_W = (const float*)d_in[13];
    const float* scalar_b = (const float*)d_in[14];
    const float* blind_W  = (const float*)d_in[15];
    const float* blind_b  = (const float*)d_in[16];
    const float* bet_W    = (const float*)d_in[17];
    const float* bet_b    = (const float*)d_in[18];
    const float* action_W = (const float*)d_in[19];
    const float* action_b = (const float*)d_in[20];
    const float* combine_W= (const float*)d_in[21];
    const float* combine_b= (const float*)d_in[22];

    float* ws  = (float*)d_ws;
    float* out = (float*)d_out;
    const int ntok = in_sizes[1];  // B*S (hero_pos flat count)

    hipLaunchKernelGGL(fuse_kernel, dim3(85), dim3(256), 0, stream,
                       combine_W, card_t, hero_t, act_t, nump_t,
                       scalar_W, scalar_b, blind_W, blind_b, bet_W, bet_b,
                       action_W, action_b, ws);
    hipLaunchKernelGGL(embed_kernel, dim3(EMB_BLOCKS), dim3(EMB_THREADS), 0, stream,
                       cards, hero, acting, nump, scalars, blinds, bets, action, mask,
                       combine_b, ws, out, ntok);
}

// Round 9
// 49.641 us; speedup vs baseline: 2.4928x; 2.4928x over previous
//
#include <hip/hip_runtime.h>

#define D 256
#define W8 2048

// workspace float offsets
#define TCARD_OFF   0                 // 53*256  (pre-scaled by 1/7)
#define THERO_OFF   13568             // 9*256
#define TACT_OFF    15872             // 9*256
#define TNUMP_OFF   18176             // 10*256
#define WSC_OFF     20736             // 2*256 (transposed [k][d])  -- rows 0..1
#define WBET_OFF    21248             // 9*256                      -- rows 2..10
#define WACT_OFF    23552             // 8*256                      -- rows 11..18
#define WBL_OFF     25600             // 2*256                      -- rows 19..20
#define BPART_OFF   26112             // 4*256 bias partials
// NOTE: WSC..WBL are 21 contiguous rows — embed_kernel copies them as one slab.

typedef float nf4 __attribute__((ext_vector_type(4)));               // native vec (nontemporal store)
typedef float f4a4 __attribute__((ext_vector_type(4), aligned(4)));  // under-aligned vec loads

__device__ __forceinline__ void f4acc(float4& a, const float4 b) {
    a.x += b.x; a.y += b.y; a.z += b.z; a.w += b.w;
}
__device__ __forceinline__ void f4fma(float4& a, float v, const float4 b) {
    a.x += v * b.x; a.y += v * b.y; a.z += v * b.z; a.w += v * b.w;
}

// -------- precompute: fold combine_W into tables & section weights --------

template <int NK>
__device__ void fuse_section(const float* __restrict__ combine_W, int wblk,
                             const float* __restrict__ sw,   // LDS [NK][D]
                             const float* __restrict__ sb,   // LDS [D]
                             float* __restrict__ dstT,       // ws [NK][D]
                             float* __restrict__ bpart,      // ws [D]
                             int d)
{
    float acc[NK];
#pragma unroll
    for (int k = 0; k < NK; ++k) acc[k] = 0.f;
    float accb = 0.f;
    const float* wrow = combine_W + (size_t)d * W8 + wblk * D;
    for (int dd = 0; dd < D; dd += 4) {
        float4 w = *(const float4*)(wrow + dd);
        accb += w.x * sb[dd] + w.y * sb[dd + 1] + w.z * sb[dd + 2] + w.w * sb[dd + 3];
#pragma unroll
        for (int k = 0; k < NK; ++k) {
            const float* s = sw + k * D + dd;
            acc[k] += w.x * s[0] + w.y * s[1] + w.z * s[2] + w.w * s[3];
        }
    }
#pragma unroll
    for (int k = 0; k < NK; ++k) dstT[k * D + d] = acc[k];
    bpart[d] = accb;
}

__global__ __launch_bounds__(256) void fuse_kernel(
    const float* __restrict__ combine_W,
    const float* __restrict__ card_t, const float* __restrict__ hero_t,
    const float* __restrict__ act_t,  const float* __restrict__ nump_t,
    const float* __restrict__ scalar_W, const float* __restrict__ scalar_b,
    const float* __restrict__ blind_W,  const float* __restrict__ blind_b,
    const float* __restrict__ bet_W,    const float* __restrict__ bet_b,
    const float* __restrict__ action_W, const float* __restrict__ action_b,
    float* __restrict__ ws)
{
    __shared__ float sh[10 * D];  // 10 KB
    const int blk = blockIdx.x;
    const int d = threadIdx.x;

    if (blk < 81) {
        // fused embedding-table rows: T[r,d] = sum_k Wblk[d,k] * table[r,k]
        const float* src; int wblk; float* dst; float scale;
        if (blk < 53)      { src = card_t + blk * D;        wblk = 0; dst = ws + TCARD_OFF + blk * D; scale = 1.0f / 7.0f; }
        else if (blk < 62) { src = hero_t + (blk - 53) * D; wblk = 1; dst = ws + THERO_OFF + (blk - 53) * D; scale = 1.0f; }
        else if (blk < 71) { src = act_t  + (blk - 62) * D; wblk = 2; dst = ws + TACT_OFF  + (blk - 62) * D; scale = 1.0f; }
        else               { src = nump_t + (blk - 71) * D; wblk = 6; dst = ws + TNUMP_OFF + (blk - 71) * D; scale = 1.0f; }
        sh[d] = src[d];
        __syncthreads();
        const float* wrow = combine_W + (size_t)d * W8 + wblk * D;
        float a0 = 0.f, a1 = 0.f, a2 = 0.f, a3 = 0.f;
#pragma unroll 8
        for (int k = 0; k < D; k += 4) {
            float4 w = *(const float4*)(wrow + k);
            a0 += w.x * sh[k];     a1 += w.y * sh[k + 1];
            a2 += w.z * sh[k + 2]; a3 += w.w * sh[k + 3];
        }
        dst[d] = ((a0 + a1) + (a2 + a3)) * scale;
    } else {
        // fused linear-section weights (stored transposed [k][d]) + bias partials
        const int sec = blk - 81;
        const float* secW; const float* secB; int nk, wblk; float* dstT;
        switch (sec) {
            case 0:  secW = scalar_W; secB = scalar_b; nk = 2; wblk = 3; dstT = ws + WSC_OFF;  break;
            case 1:  secW = bet_W;    secB = bet_b;    nk = 9; wblk = 4; dstT = ws + WBET_OFF; break;
            case 2:  secW = action_W; secB = action_b; nk = 8; wblk = 5; dstT = ws + WACT_OFF; break;
            default: secW = blind_W;  secB = blind_b;  nk = 2; wblk = 7; dstT = ws + WBL_OFF;  break;
        }
        for (int k = 0; k < nk; ++k) sh[k * D + d] = secW[d * nk + k];  // transpose into LDS
        sh[9 * D + d] = secB[d];
        __syncthreads();
        float* bpart = ws + BPART_OFF + sec * D;
        if (nk == 2)      fuse_section<2>(combine_W, wblk, sh, sh + 9 * D, dstT, bpart, d);
        else if (nk == 8) fuse_section<8>(combine_W, wblk, sh, sh + 9 * D, dstT, bpart, d);
        else              fuse_section<9>(combine_W, wblk, sh, sh + 9 * D, dstT, bpart, d);
    }
}

// -------- main: R5 structure, natural VGPR (NO min-waves cap), 2048 blocks --
// R2/R8 lesson: ANY launch_bounds min-waves below the body's natural VGPR
// (~55-90) causes catastrophic scratch spill (FETCH 214-308 MB). Occupancy
// must come from natural register count: TPW=1 body ~50-64 VGPR, LDS 22.5 KB
// -> 7 blocks/CU x 4 waves = 28 waves/CU.

#define EMB_BLOCKS 2048
#define EMB_THREADS 256
#define EMB_WAVES (EMB_THREADS / 64)
#define WROWS 22   // 21 weight rows + 1 fused-bias row

__global__ __launch_bounds__(EMB_THREADS) void embed_kernel(
    const int* __restrict__ cards,  const int* __restrict__ hero,
    const int* __restrict__ acting, const int* __restrict__ nump,
    const float* __restrict__ scalars, const float* __restrict__ blinds,
    const float* __restrict__ bets,    const float* __restrict__ action,
    const float* __restrict__ mask,    const float* __restrict__ combine_b,
    const float* __restrict__ ws, float* __restrict__ out, int ntok)
{
    __shared__ __align__(16) float wlds[WROWS * D];  // 22528 B

    const int tid = threadIdx.x;

    // rows 0..20: one contiguous slab ws[WSC_OFF .. WSC_OFF+21*256)
    {
        const float4* src = (const float4*)(ws + WSC_OFF);
        float4* dst = (float4*)wlds;
        for (int i = tid; i < 21 * (D / 4); i += EMB_THREADS) dst[i] = src[i];
        // row 21: fused bias = combine_b + 4 section-bias partials
        wlds[21 * D + tid] = combine_b[tid]
            + ws[BPART_OFF + 0 * D + tid] + ws[BPART_OFF + 1 * D + tid]
            + ws[BPART_OFF + 2 * D + tid] + ws[BPART_OFF + 3 * D + tid];
    }
    __syncthreads();

    const int lane = tid & 63;
    const int wave = tid >> 6;
    const int d0 = lane * 4;

    const int gw = blockIdx.x * EMB_WAVES + wave;
    const int nw = EMB_BLOCKS * EMB_WAVES;

    for (int tok = gw; tok < ntok; tok += nw) {
        // acc0: gathers (cards + embeds) + bias; acc1: sections — two chains
        float4 acc0 = *(const float4*)(wlds + 21 * D + d0);  // bias
        float4 acc1 = {0.f, 0.f, 0.f, 0.f};

        // contiguous, mergeable feature loads (vectorized)
        const f4a4 bt0 = *(const f4a4*)(bets + (size_t)tok * 9);
        const f4a4 bt1 = *(const f4a4*)(bets + (size_t)tok * 9 + 4);
        const float bt8 = bets[(size_t)tok * 9 + 8];
        const float4 fa0 = *(const float4*)(action + (size_t)tok * 8);
        const float4 fa1 = *(const float4*)(action + (size_t)tok * 8 + 4);
        const float2 fs = *(const float2*)(scalars + (size_t)tok * 2);
        const float2 fl = *(const float2*)(blinds + (size_t)tok * 2);
        const float m = mask[tok];

        // gathers from L2-resident ws
        const int* cp = cards + (size_t)tok * 7;
#pragma unroll
        for (int j = 0; j < 7; ++j)
            f4acc(acc0, *(const float4*)(ws + TCARD_OFF + cp[j] * D + d0));
        f4acc(acc0, *(const float4*)(ws + THERO_OFF + hero[tok]   * D + d0));
        f4acc(acc0, *(const float4*)(ws + TACT_OFF  + acting[tok] * D + d0));
        f4acc(acc0, *(const float4*)(ws + TNUMP_OFF + nump[tok]   * D + d0));

        // 21-row LDS weight sweep
        f4fma(acc1, fs.x,  *(const float4*)(wlds + 0  * D + d0));
        f4fma(acc1, fs.y,  *(const float4*)(wlds + 1  * D + d0));
        f4fma(acc1, bt0.x, *(const float4*)(wlds + 2  * D + d0));
        f4fma(acc1, bt0.y, *(const float4*)(wlds + 3  * D + d0));
        f4fma(acc1, bt0.z, *(const float4*)(wlds + 4  * D + d0));
        f4fma(acc1, bt0.w, *(const float4*)(wlds + 5  * D + d0));
        f4fma(acc1, bt1.x, *(const float4*)(wlds + 6  * D + d0));
        f4fma(acc1, bt1.y, *(const float4*)(wlds + 7  * D + d0));
        f4fma(acc1, bt1.z, *(const float4*)(wlds + 8  * D + d0));
        f4fma(acc1, bt1.w, *(const float4*)(wlds + 9  * D + d0));
        f4fma(acc1, bt8,   *(const float4*)(wlds + 10 * D + d0));
        f4fma(acc1, fa0.x, *(const float4*)(wlds + 11 * D + d0));
        f4fma(acc1, fa0.y, *(const float4*)(wlds + 12 * D + d0));
        f4fma(acc1, fa0.z, *(const float4*)(wlds + 13 * D + d0));
        f4fma(acc1, fa0.w, *(const float4*)(wlds + 14 * D + d0));
        f4fma(acc1, fa1.x, *(const float4*)(wlds + 15 * D + d0));
        f4fma(acc1, fa1.y, *(const float4*)(wlds + 16 * D + d0));
        f4fma(acc1, fa1.z, *(const float4*)(wlds + 17 * D + d0));
        f4fma(acc1, fa1.w, *(const float4*)(wlds + 18 * D + d0));
        f4fma(acc1, fl.x,  *(const float4*)(wlds + 19 * D + d0));
        f4fma(acc1, fl.y,  *(const float4*)(wlds + 20 * D + d0));

        nf4 o;
        o.x = (acc0.x + acc1.x) * m; o.y = (acc0.y + acc1.y) * m;
        o.z = (acc0.z + acc1.z) * m; o.w = (acc0.w + acc1.w) * m;
        __builtin_nontemporal_store(o, (nf4*)(out + (size_t)tok * D + d0));
    }
}

extern "C" void kernel_launch(void* const* d_in, const int* in_sizes, int n_in,
                              void* d_out, int out_size, void* d_ws, size_t ws_size,
                              hipStream_t stream) {
    const int*   cards    = (const int*)d_in[0];
    const int*   hero     = (const int*)d_in[1];
    const int*   acting   = (const int*)d_in[2];
    const int*   nump     = (const int*)d_in[3];
    const float* scalars  = (const float*)d_in[4];
    const float* blinds   = (const float*)d_in[5];
    const float* bets     = (const float*)d_in[6];
    const float* action   = (const float*)d_in[7];
    const float* mask     = (const float*)d_in[8];
    const float* card_t   = (const float*)d_in[9];
    const float* hero_t   = (const float*)d_in[10];
    const float* act_t    = (const float*)d_in[11];
    const float* nump_t   = (const float*)d_in[12];
    const float* scalar_W = (const float*)d_in[13];
    const float* scalar_b = (const float*)d_in[14];
    const float* blind_W  = (const float*)d_in[15];
    const float* blind_b  = (const float*)d_in[16];
    const float* bet_W    = (const float*)d_in[17];
    const float* bet_b    = (const float*)d_in[18];
    const float* action_W = (const float*)d_in[19];
    const float* action_b = (const float*)d_in[20];
    const float* combine_W= (const float*)d_in[21];
    const float* combine_b= (const float*)d_in[22];

    float* ws  = (float*)d_ws;
    float* out = (float*)d_out;
    const int ntok = in_sizes[1];  // B*S (hero_pos flat count)

    hipLaunchKernelGGL(fuse_kernel, dim3(85), dim3(256), 0, stream,
                       combine_W, card_t, hero_t, act_t, nump_t,
                       scalar_W, scalar_b, blind_W, blind_b, bet_W, bet_b,
                       action_W, action_b, ws);
    hipLaunchKernelGGL(embed_kernel, dim3(EMB_BLOCKS), dim3(EMB_THREADS), 0, stream,
                       cards, hero, acting, nump, scalars, blinds, bets, action, mask,
                       combine_b, ws, out, ntok);
}

// Round 10
// 39.206 us; speedup vs baseline: 3.1563x; 1.2662x over previous
//
#include <hip/hip_runtime.h>

#define D 256
#define W8 2048

// workspace float offsets
#define TCARD_OFF   0                 // (legacy f32 region, unused by embed now)
#define THERO_OFF   13568
#define TACT_OFF    15872
#define TNUMP_OFF   18176
#define WSC_OFF     20736             // 2*256 (transposed [k][d])  -- rows 0..1
#define WBET_OFF    21248             // 9*256                      -- rows 2..10
#define WACT_OFF    23552             // 8*256                      -- rows 11..18
#define WBL_OFF     25600             // 2*256                      -- rows 19..20
#define BPART_OFF   26112             // 4*256 bias partials
#define TB16_OFF    27392             // bf16 table: 81 rows * 256 ushort (41.5 KB)
// rows 0..52 card (pre-scaled 1/7), 53..61 hero, 62..70 acting, 71..80 nump

typedef float nf4 __attribute__((ext_vector_type(4)));  // native vec (nontemporal store)

__device__ __forceinline__ void f4acc(float4& a, const float4 b) {
    a.x += b.x; a.y += b.y; a.z += b.z; a.w += b.w;
}
__device__ __forceinline__ void f4fma(float4& a, float v, const float4 b) {
    a.x += v * b.x; a.y += v * b.y; a.z += v * b.z; a.w += v * b.w;
}

// bf16 row gather: 8B/lane, expand with <<16
__device__ __forceinline__ float4 bf16row(const ushort* __restrict__ tb, int row, int e0) {
    const ushort4 u = *(const ushort4*)(tb + row * D + e0);
    float4 v;
    v.x = __uint_as_float((unsigned)u.x << 16);
    v.y = __uint_as_float((unsigned)u.y << 16);
    v.z = __uint_as_float((unsigned)u.z << 16);
    v.w = __uint_as_float((unsigned)u.w << 16);
    return v;
}

// -------- precompute: fold combine_W into tables & section weights --------

template <int NK>
__device__ void fuse_section(const float* __restrict__ combine_W, int wblk,
                             const float* __restrict__ sw,   // LDS [NK][D]
                             const float* __restrict__ sb,   // LDS [D]
                             float* __restrict__ dstT,       // ws [NK][D]
                             float* __restrict__ bpart,      // ws [D]
                             int d)
{
    float acc[NK];
#pragma unroll
    for (int k = 0; k < NK; ++k) acc[k] = 0.f;
    float accb = 0.f;
    const float* wrow = combine_W + (size_t)d * W8 + wblk * D;
    for (int dd = 0; dd < D; dd += 4) {
        float4 w = *(const float4*)(wrow + dd);
        accb += w.x * sb[dd] + w.y * sb[dd + 1] + w.z * sb[dd + 2] + w.w * sb[dd + 3];
#pragma unroll
        for (int k = 0; k < NK; ++k) {
            const float* s = sw + k * D + dd;
            acc[k] += w.x * s[0] + w.y * s[1] + w.z * s[2] + w.w * s[3];
        }
    }
#pragma unroll
    for (int k = 0; k < NK; ++k) dstT[k * D + d] = acc[k];
    bpart[d] = accb;
}

__global__ __launch_bounds__(256) void fuse_kernel(
    const float* __restrict__ combine_W,
    const float* __restrict__ card_t, const float* __restrict__ hero_t,
    const float* __restrict__ act_t,  const float* __restrict__ nump_t,
    const float* __restrict__ scalar_W, const float* __restrict__ scalar_b,
    const float* __restrict__ blind_W,  const float* __restrict__ blind_b,
    const float* __restrict__ bet_W,    const float* __restrict__ bet_b,
    const float* __restrict__ action_W, const float* __restrict__ action_b,
    float* __restrict__ ws)
{
    __shared__ float sh[10 * D];  // 10 KB
    const int blk = blockIdx.x;
    const int d = threadIdx.x;

    if (blk < 81) {
        // fused embedding-table rows: T[r,d] = sum_k Wblk[d,k] * table[r,k]
        const float* src; int wblk; float scale;
        if (blk < 53)      { src = card_t + blk * D;        wblk = 0; scale = 1.0f / 7.0f; }
        else if (blk < 62) { src = hero_t + (blk - 53) * D; wblk = 1; scale = 1.0f; }
        else if (blk < 71) { src = act_t  + (blk - 62) * D; wblk = 2; scale = 1.0f; }
        else               { src = nump_t + (blk - 71) * D; wblk = 6; scale = 1.0f; }
        sh[d] = src[d];
        __syncthreads();
        const float* wrow = combine_W + (size_t)d * W8 + wblk * D;
        float a0 = 0.f, a1 = 0.f, a2 = 0.f, a3 = 0.f;
#pragma unroll 8
        for (int k = 0; k < D; k += 4) {
            float4 w = *(const float4*)(wrow + k);
            a0 += w.x * sh[k];     a1 += w.y * sh[k + 1];
            a2 += w.z * sh[k + 2]; a3 += w.w * sh[k + 3];
        }
        const float v = ((a0 + a1) + (a2 + a3)) * scale;
        // bf16 RNE into the unified 81-row table (row == blk)
        const unsigned x = __float_as_uint(v);
        ((ushort*)(ws + TB16_OFF))[blk * D + d] =
            (ushort)((x + 0x7fffu + ((x >> 16) & 1u)) >> 16);
    } else {
        // fused linear-section weights (stored transposed [k][d]) + bias partials
        const int sec = blk - 81;
        const float* secW; const float* secB; int nk, wblk; float* dstT;
        switch (sec) {
            case 0:  secW = scalar_W; secB = scalar_b; nk = 2; wblk = 3; dstT = ws + WSC_OFF;  break;
            case 1:  secW = bet_W;    secB = bet_b;    nk = 9; wblk = 4; dstT = ws + WBET_OFF; break;
            case 2:  secW = action_W; secB = action_b; nk = 8; wblk = 5; dstT = ws + WACT_OFF; break;
            default: secW = blind_W;  secB = blind_b;  nk = 2; wblk = 7; dstT = ws + WBL_OFF;  break;
        }
        for (int k = 0; k < nk; ++k) sh[k * D + d] = secW[d * nk + k];  // transpose into LDS
        sh[9 * D + d] = secB[d];
        __syncthreads();
        float* bpart = ws + BPART_OFF + sec * D;
        if (nk == 2)      fuse_section<2>(combine_W, wblk, sh, sh + 9 * D, dstT, bpart, d);
        else if (nk == 8) fuse_section<8>(combine_W, wblk, sh, sh + 9 * D, dstT, bpart, d);
        else              fuse_section<9>(combine_W, wblk, sh, sh + 9 * D, dstT, bpart, d);
    }
}

// -------- main: R5 structure + bf16 gather tables (halved L2 gather bytes) --
// R9 lesson: occupancy is not the lever (26% occ slower than R5); VALU 10%,
// HBM 8% -> the floor is ~360 MB of 1KB random-row L2 gathers. bf16 tables
// halve that to 180 MB, and the 27 KB bf16 card table now fits L1.
// R2/R8 lesson: no launch_bounds min-waves cap (spill). R5 params: 1024
// blocks, TPW=1, scalar bets loads, f32 weight slab in 22.5 KB LDS.

#define EMB_BLOCKS 1024
#define EMB_THREADS 256
#define EMB_WAVES (EMB_THREADS / 64)
#define WROWS 22   // 21 weight rows + 1 fused-bias row

__global__ __launch_bounds__(EMB_THREADS) void embed_kernel(
    const int* __restrict__ cards,  const int* __restrict__ hero,
    const int* __restrict__ acting, const int* __restrict__ nump,
    const float* __restrict__ scalars, const float* __restrict__ blinds,
    const float* __restrict__ bets,    const float* __restrict__ action,
    const float* __restrict__ mask,    const float* __restrict__ combine_b,
    const float* __restrict__ ws, float* __restrict__ out, int ntok)
{
    __shared__ __align__(16) float wlds[WROWS * D];  // 22528 B

    const int tid = threadIdx.x;

    // rows 0..20: one contiguous slab ws[WSC_OFF .. WSC_OFF+21*256)
    {
        const float4* src = (const float4*)(ws + WSC_OFF);
        float4* dst = (float4*)wlds;
        for (int i = tid; i < 21 * (D / 4); i += EMB_THREADS) dst[i] = src[i];
        // row 21: fused bias = combine_b + 4 section-bias partials
        wlds[21 * D + tid] = combine_b[tid]
            + ws[BPART_OFF + 0 * D + tid] + ws[BPART_OFF + 1 * D + tid]
            + ws[BPART_OFF + 2 * D + tid] + ws[BPART_OFF + 3 * D + tid];
    }
    __syncthreads();

    const int lane = tid & 63;
    const int wave = tid >> 6;
    const int d0 = lane * 4;

    const ushort* tb = (const ushort*)(ws + TB16_OFF);

    const int gw = blockIdx.x * EMB_WAVES + wave;
    const int nw = EMB_BLOCKS * EMB_WAVES;

    for (int tok = gw; tok < ntok; tok += nw) {
        // acc0: gathers (cards + embeds) + bias; acc1: sections — two chains
        float4 acc0 = *(const float4*)(wlds + 21 * D + d0);  // bias
        float4 acc1 = {0.f, 0.f, 0.f, 0.f};

        // bf16 gathers (8B/lane) from L1/L2-resident table
        const int* cp = cards + (size_t)tok * 7;
#pragma unroll
        for (int j = 0; j < 7; ++j)
            f4acc(acc0, bf16row(tb, cp[j], d0));
        f4acc(acc0, bf16row(tb, 53 + hero[tok],   d0));
        f4acc(acc0, bf16row(tb, 62 + acting[tok], d0));
        f4acc(acc0, bf16row(tb, 71 + nump[tok],   d0));

        // contiguous feature loads
        const float2 fs = *(const float2*)(scalars + (size_t)tok * 2);
        f4fma(acc1, fs.x, *(const float4*)(wlds + 0 * D + d0));
        f4fma(acc1, fs.y, *(const float4*)(wlds + 1 * D + d0));

        const float* fb = bets + (size_t)tok * 9;
#pragma unroll
        for (int k = 0; k < 9; ++k)
            f4fma(acc1, fb[k], *(const float4*)(wlds + (2 + k) * D + d0));

        const float4 fa0 = *(const float4*)(action + (size_t)tok * 8);
        const float4 fa1 = *(const float4*)(action + (size_t)tok * 8 + 4);
        f4fma(acc1, fa0.x, *(const float4*)(wlds + 11 * D + d0));
        f4fma(acc1, fa0.y, *(const float4*)(wlds + 12 * D + d0));
        f4fma(acc1, fa0.z, *(const float4*)(wlds + 13 * D + d0));
        f4fma(acc1, fa0.w, *(const float4*)(wlds + 14 * D + d0));
        f4fma(acc1, fa1.x, *(const float4*)(wlds + 15 * D + d0));
        f4fma(acc1, fa1.y, *(const float4*)(wlds + 16 * D + d0));
        f4fma(acc1, fa1.z, *(const float4*)(wlds + 17 * D + d0));
        f4fma(acc1, fa1.w, *(const float4*)(wlds + 18 * D + d0));

        const float2 fl = *(const float2*)(blinds + (size_t)tok * 2);
        f4fma(acc1, fl.x, *(const float4*)(wlds + 19 * D + d0));
        f4fma(acc1, fl.y, *(const float4*)(wlds + 20 * D + d0));

        const float m = mask[tok];
        nf4 o;
        o.x = (acc0.x + acc1.x) * m; o.y = (acc0.y + acc1.y) * m;
        o.z = (acc0.z + acc1.z) * m; o.w = (acc0.w + acc1.w) * m;
        __builtin_nontemporal_store(o, (nf4*)(out + (size_t)tok * D + d0));
    }
}

extern "C" void kernel_launch(void* const* d_in, const int* in_sizes, int n_in,
                              void* d_out, int out_size, void* d_ws, size_t ws_size,
                              hipStream_t stream) {
    const int*   cards    = (const int*)d_in[0];
    const int*   hero     = (const int*)d_in[1];
    const int*   acting   = (const int*)d_in[2];
    const int*   nump     = (const int*)d_in[3];
    const float* scalars  = (const float*)d_in[4];
    const float* blinds   = (const float*)d_in[5];
    const float* bets     = (const float*)d_in[6];
    const float* action   = (const float*)d_in[7];
    const float* mask     = (const float*)d_in[8];
    const float* card_t   = (const float*)d_in[9];
    const float* hero_t   = (const float*)d_in[10];
    const float* act_t    = (const float*)d_in[11];
    const float* nump_t   = (const float*)d_in[12];
    const float* scalar_W = (const float*)d_in[13];
    const float* scalar_b = (const float*)d_in[14];
    const float* blind_W  = (const float*)d_in[15];
    const float* blind_b  = (const float*)d_in[16];
    const float* bet_W    = (const float*)d_in[17];
    const float* bet_b    = (const float*)d_in[18];
    const float* action_W = (const float*)d_in[19];
    const float* action_b = (const float*)d_in[20];
    const float* combine_W= (const float*)d_in[21];
    const float* combine_b= (const float*)d_in[22];

    float* ws  = (float*)d_ws;
    float* out = (float*)d_out;
    const int ntok = in_sizes[1];  // B*S (hero_pos flat count)

    hipLaunchKernelGGL(fuse_kernel, dim3(85), dim3(256), 0, stream,
                       combine_W, card_t, hero_t, act_t, nump_t,
                       scalar_W, scalar_b, blind_W, blind_b, bet_W, bet_b,
                       action_W, action_b, ws);
    hipLaunchKernelGGL(embed_kernel, dim3(EMB_BLOCKS), dim3(EMB_THREADS), 0, stream,
                       cards, hero, acting, nump, scalars, blinds, bets, action, mask,
                       combine_b, ws, out, ntok);
}